// Round 1
// baseline (1730.357 us; speedup 1.0000x reference)
//
#include <hip/hip_runtime.h>
#include <hip/hip_bf16.h>

// PhaseNet: B=2,S=2048,D=1024,H=64,C=4,V=50257
// x = embed[tokens]
// 4x: hn = rms(x)*nw*g+b ; x += 0.3*silu(out_scale*(hn + R@hn) + dwconv3(hn))
// out = rms(x, onw) @ W^T
//
// phase_layer is linear on the D axis: irfft(mix(rfft)) = I + R, R precomputed
// on device from phase_angles/interference. GEMMs in bf16 MFMA (16x16x32),
// m97-style 128x128 tile with global_load_lds width=16.

#define TWO_PI 6.283185307179586f

typedef __bf16 bf16x8 __attribute__((ext_vector_type(8)));
typedef float  f32x4  __attribute__((ext_vector_type(4)));

static __device__ __forceinline__ unsigned short f2bf(float f){
  union { float f; unsigned int u; } v; v.f = f;
  unsigned int r = v.u + 0x7fffu + ((v.u >> 16) & 1u);   // RNE
  return (unsigned short)(r >> 16);
}
static __device__ __forceinline__ float bf2f(unsigned short u){
  union { unsigned int u; float f; } v; v.u = ((unsigned int)u) << 16;
  return v.f;
}

#define GLDS16(g, l) __builtin_amdgcn_global_load_lds( \
    (const __attribute__((address_space(1))) unsigned int*)(g), \
    (__attribute__((address_space(3))) unsigned int*)(l), 16, 0, 0)

// ---------------- embed gather ----------------
__global__ __launch_bounds__(256) void k_embed(const int* __restrict__ tok,
                                               const float* __restrict__ emb,
                                               float* __restrict__ x){
  const int t = blockIdx.x;
  const int v = tok[t];
  const float4* src = (const float4*)(emb + (size_t)v * 1024);
  float4* dst = (float4*)(x + (size_t)t * 1024);
  dst[threadIdx.x] = src[threadIdx.x];
}

// ---------------- lm_head weight f32 -> bf16 (padded to 50304 rows) --------
__global__ __launch_bounds__(256) void k_wcvt(const float* __restrict__ W,
                                              unsigned short* __restrict__ Wb){
  const size_t i4 = (size_t)blockIdx.x * 256 + threadIdx.x;
  const size_t e = i4 * 4;
  const int row = (int)(e >> 10);
  ushort4 o4;
  if (row < 50257){
    float4 v = *(const float4*)(W + e);
    o4 = make_ushort4(f2bf(v.x), f2bf(v.y), f2bf(v.z), f2bf(v.w));
  } else {
    o4 = make_ushort4(0, 0, 0, 0);
  }
  *(ushort4*)(Wb + e) = o4;
}

// ---------------- phase operator precompute --------------------------------
// G[k,j] = sum_h e^{-2pi i h j/1024} ph_h M[h,k]  -  e^{-2pi i k j/1024}, k<64
__global__ __launch_bounds__(256) void k_G(const float* __restrict__ pa,
                                           const float* __restrict__ inter,
                                           float* __restrict__ Gre,
                                           float* __restrict__ Gim){
  __shared__ float tc[1024], tsn[1024], pc[64], ps[64];
  const int tid = threadIdx.x;
  for (int i = tid; i < 1024; i += 256){
    float a = (float)i * (TWO_PI / 1024.f);
    tc[i] = cosf(a); tsn[i] = sinf(a);
  }
  if (tid < 64){ float a = pa[tid]; pc[tid] = cosf(a); ps[tid] = sinf(a); }
  __syncthreads();
  const int idx = blockIdx.x * 256 + tid;
  const int k = idx >> 10, j = idx & 1023;
  float sre = 0.f, sim = 0.f;
  for (int h = 0; h < 64; h++){
    int m = (h * j) & 1023;              // exact angle reduction
    float c = tc[m], sn = tsn[m];
    float Mhk = inter[h * 64 + k];
    sre += Mhk * (c * pc[h] + sn * ps[h]);
    sim += Mhk * (c * ps[h] - sn * pc[h]);
  }
  const int mk = (k * j) & 1023;
  Gre[idx] = sre - tc[mk];
  Gim[idx] = sim + tsn[mk];
}

// R[d,j] = (1/1024) sum_k c_k (Gre[k,j] cos(2pi k d/1024) - Gim[k,j] sin(...))
__global__ __launch_bounds__(256) void k_R(const float* __restrict__ Gre,
                                           const float* __restrict__ Gim,
                                           unsigned short* __restrict__ Rb){
  __shared__ float tc[1024], tsn[1024];
  const int tid = threadIdx.x;
  for (int i = tid; i < 1024; i += 256){
    float a = (float)i * (TWO_PI / 1024.f);
    tc[i] = cosf(a); tsn[i] = sinf(a);
  }
  __syncthreads();
  const int idx = blockIdx.x * 256 + tid;
  const int d = idx >> 10, j = idx & 1023;
  float acc = 0.f;
  for (int k = 0; k < 64; k++){
    int m = (k * d) & 1023;
    float ckk = (k == 0) ? 1.f : 2.f;
    acc += ckk * (Gre[k * 1024 + j] * tc[m] - Gim[k * 1024 + j] * tsn[m]);
  }
  Rb[idx] = f2bf(acc * (1.f / 1024.f));   // stored [d][j] = B^T layout for GEMM
}

// ---------------- RMS norm (+ optional affine) -> bf16 ----------------------
__global__ __launch_bounds__(256) void k_rms(const float* __restrict__ x,
    const float* __restrict__ nw, const float* __restrict__ gm,
    const float* __restrict__ bt, unsigned short* __restrict__ hout,
    float* __restrict__ rstd_out){
  const int t = blockIdx.x, tid = threadIdx.x;
  const size_t base = (size_t)t * 1024;
  float4 v = *(const float4*)(x + base + tid * 4);
  float ss = v.x*v.x + v.y*v.y + v.z*v.z + v.w*v.w;
  #pragma unroll
  for (int o = 32; o; o >>= 1) ss += __shfl_xor(ss, o);
  __shared__ float wsum[4];
  if ((tid & 63) == 0) wsum[tid >> 6] = ss;
  __syncthreads();
  float rs = rsqrtf((wsum[0]+wsum[1]+wsum[2]+wsum[3]) * (1.f/1024.f)
                    + 1.1920928955078125e-07f);
  if (rstd_out != nullptr && tid == 0) rstd_out[t] = rs;
  const int c0 = tid * 4;
  float h[4] = {v.x, v.y, v.z, v.w};
  ushort4 o4;
  unsigned short* po = (unsigned short*)&o4;
  #pragma unroll
  for (int j = 0; j < 4; j++){
    float hv = h[j] * rs * nw[c0 + j];
    if (gm) hv = hv * gm[c0 + j] + bt[c0 + j];
    po[j] = f2bf(hv);
  }
  *(ushort4*)(hout + base + c0) = o4;
}

// ---------------- conv + silu + residual ------------------------------------
__global__ __launch_bounds__(256) void k_mix(float* __restrict__ x,
    const float* __restrict__ tmp, const unsigned short* __restrict__ hn,
    const float* __restrict__ rstd, const float* __restrict__ nw,
    const float* __restrict__ gm, const float* __restrict__ bt,
    const float* __restrict__ osc, const float* __restrict__ ckr){
  const int t = blockIdx.x, tid = threadIdx.x;
  const int s = t & 2047;                       // S = 2048
  const size_t base = (size_t)t * 1024;
  const int c0 = tid * 4;
  float4 xv = *(const float4*)(x + base + c0);
  float4 tv = *(const float4*)(tmp + base + c0);
  ushort4 hc = *(const ushort4*)(hn + base + c0);
  ushort4 hl = make_ushort4(0,0,0,0), hr = make_ushort4(0,0,0,0);
  if (s > 0)    hl = *(const ushort4*)(hn + base - 1024 + c0);
  if (s < 2047) hr = *(const ushort4*)(hn + base + 1024 + c0);
  const float rs = rstd[t];
  float xa[4] = {xv.x, xv.y, xv.z, xv.w};
  float ta[4] = {tv.x, tv.y, tv.z, tv.w};
  unsigned short hca[4] = {hc.x, hc.y, hc.z, hc.w};
  unsigned short hla[4] = {hl.x, hl.y, hl.z, hl.w};
  unsigned short hra[4] = {hr.x, hr.y, hr.z, hr.w};
  float res[4];
  #pragma unroll
  for (int j = 0; j < 4; j++){
    const int d = c0 + j;
    float hnf = xa[j] * rs * nw[d] * gm[d] + bt[d];       // f32 hn (diag term)
    float pre = osc[d] * (hnf + ta[j]);                   // out_scale*(hn + R hn)
    float cv = ckr[d*3+0]*bf2f(hla[j]) + ckr[d*3+1]*bf2f(hca[j])
             + ckr[d*3+2]*bf2f(hra[j]);                   // cross-correlation
    float z = pre + cv;
    float sil = z / (1.f + expf(-z));
    res[j] = xa[j] + 0.3f * sil;
  }
  *(float4*)(x + base + c0) = *(float4*)res;
}

// ---------------- bf16 GEMM, C[m,n] = sum_k A[m,k]*B[n,k] -------------------
// m97 structure: 128x128 tile, BK=64, 4 waves (2x2 of 64x64), global_load_lds,
// 2 barriers per K-step. Linear LDS (no swizzle yet).
__global__ __launch_bounds__(256, 2)
void k_gemm_bt(const unsigned short* __restrict__ A,
               const unsigned short* __restrict__ Bm,
               float* __restrict__ C,
               int K, int ldc, int Nout){
  constexpr int BM = 128, BN = 128, BK = 64;
  __shared__ __align__(16) unsigned short lA[BM * BK];
  __shared__ __align__(16) unsigned short lB[BN * BK];
  const int tid = threadIdx.x;
  const int wid = tid >> 6, lane = tid & 63;
  const int rowA0 = blockIdx.x * BM, rowB0 = blockIdx.y * BN;
  const int wm = (wid >> 1) * 64, wn = (wid & 1) * 64;
  const int lr = lane >> 3, lc8 = (lane & 7) * 8;   // chunk = 8 rows x 128B
  f32x4 acc[4][4] = {};
  for (int k0 = 0; k0 < K; k0 += BK){
    #pragma unroll
    for (int i = 0; i < 4; i++){
      const int c = wid * 4 + i;                    // 16 chunks of 1KB each
      GLDS16(A  + (size_t)(rowA0 + c*8 + lr) * K + (k0 + lc8), &lA[c * 512]);
      GLDS16(Bm + (size_t)(rowB0 + c*8 + lr) * K + (k0 + lc8), &lB[c * 512]);
    }
    __syncthreads();
    #pragma unroll
    for (int ks = 0; ks < 2; ks++){
      const int kc = ks * 32 + (lane >> 4) * 8;
      const int rsel = lane & 15;
      bf16x8 af[4], bfr[4];
      #pragma unroll
      for (int i = 0; i < 4; i++){
        af[i]  = *(const bf16x8*)(&lA[(wm + i*16 + rsel) * BK + kc]);
        bfr[i] = *(const bf16x8*)(&lB[(wn + i*16 + rsel) * BK + kc]);
      }
      #pragma unroll
      for (int i = 0; i < 4; i++)
        #pragma unroll
        for (int j = 0; j < 4; j++)
          acc[i][j] = __builtin_amdgcn_mfma_f32_16x16x32_bf16(af[i], bfr[j],
                                                              acc[i][j], 0, 0, 0);
    }
    __syncthreads();
  }
  // C/D layout: col = lane&15, row = (lane>>4)*4 + reg   [verified m89/m91]
  const int cl = lane & 15, rq = (lane >> 4) * 4;
  #pragma unroll
  for (int i = 0; i < 4; i++){
    #pragma unroll
    for (int j = 0; j < 4; j++){
      const int cc = rowB0 + wn + j*16 + cl;
      if (cc < Nout){
        const int r0 = rowA0 + wm + i*16 + rq;
        #pragma unroll
        for (int r = 0; r < 4; r++)
          C[(size_t)(r0 + r) * ldc + cc] = acc[i][j][r];
      }
    }
  }
}

extern "C" void kernel_launch(void* const* d_in, const int* in_sizes, int n_in,
                              void* d_out, int out_size, void* d_ws, size_t ws_size,
                              hipStream_t stream){
  const int*   tok   = (const int*)  d_in[0];
  const float* emb   = (const float*)d_in[1];
  const float* pa    = (const float*)d_in[2];
  const float* inter = (const float*)d_in[3];
  const float* osc   = (const float*)d_in[4];
  const float* gms   = (const float*)d_in[5];
  const float* bts   = (const float*)d_in[6];
  const float* nws   = (const float*)d_in[7];
  const float* ckr   = (const float*)d_in[8];
  const float* onw   = (const float*)d_in[9];
  const float* lmw   = (const float*)d_in[10];
  float* out = (float*)d_out;

  // workspace carve-up (~153.5 MB total)
  char* p = (char*)d_ws;
  auto alloc = [&](size_t bytes) -> char* {
    char* r = p; p += (bytes + 255) & ~(size_t)255; return r;
  };
  float*          x    = (float*)         alloc(4096ull * 1024 * 4);
  float*          tmp  = (float*)         alloc(4096ull * 1024 * 4);
  unsigned short* hn   = (unsigned short*)alloc(4096ull * 1024 * 2);
  unsigned short* xn   = (unsigned short*)alloc(4096ull * 1024 * 2);
  float*          rstd = (float*)         alloc(4096 * 4);
  float*          Gre  = (float*)         alloc(64ull * 1024 * 4);
  float*          Gim  = (float*)         alloc(64ull * 1024 * 4);
  unsigned short* Rb   = (unsigned short*)alloc(1024ull * 1024 * 2);
  unsigned short* Wb   = (unsigned short*)alloc(50304ull * 1024 * 2);

  k_wcvt <<<50304, 256, 0, stream>>>(lmw, Wb);
  k_embed<<<4096,  256, 0, stream>>>(tok, emb, x);
  k_G    <<<256,   256, 0, stream>>>(pa, inter, Gre, Gim);
  k_R    <<<4096,  256, 0, stream>>>(Gre, Gim, Rb);

  for (int c = 0; c < 4; c++){
    k_rms<<<4096, 256, 0, stream>>>(x, nws + c*1024, gms + c*1024, bts + c*1024,
                                    hn, rstd);
    k_gemm_bt<<<dim3(32, 8), 256, 0, stream>>>(hn, Rb, tmp, 1024, 1024, 1024);
    k_mix<<<4096, 256, 0, stream>>>(x, tmp, hn, rstd, nws + c*1024,
                                    gms + c*1024, bts + c*1024, osc, ckr);
  }

  k_rms<<<4096, 256, 0, stream>>>(x, onw, nullptr, nullptr, xn, nullptr);
  // lm_head: M=4096, N=50304 (padded, zero rows), stores guarded to 50257
  k_gemm_bt<<<dim3(32, 393), 256, 0, stream>>>(xn, Wb, out, 1024, 50257, 50257);
}